// Round 11
// baseline (128.967 us; speedup 1.0000x reference)
//
#include <hip/hip_runtime.h>
#include <hip/hip_bf16.h>

// out[b,h,w,dy*9+dx] = leaky_relu( mean_c( prv[b,h,w,c] * nxt[b,h+dy-4,w+dx-4,c] ), 0.1 )
// R11: R10's coalesced banded-MFMA core with:
//  - KS=32 (NK=6): LDS 22.7 KB -> more resident blocks (target 5/CU) for cross-block
//    latency hiding (R10 had 3; occupancy was the limiter).
//  - XCD-chunked block swizzle: b = bid&7 -> each XCD owns one batch image; halo
//    re-reads hit its private L2.
//  - staging granule = 4ch = 16B dwordx4; wave = 8 px x 8 granules = 16 lines (ideal).

#define B_ 8
#define H_ 128
#define W_ 128
#define C_ 192
#define ND 9
#define NDISP 81
#define HT 4            // output rows per block (one per wave)
#define WT 16           // output cols per block
#define KS 32           // channels per k-step
#define NK 6            // 192/32
#define BROWS 12        // HT + ND - 1 nxt rows staged
#define BCOLS 24        // WT + 8 nxt cols staged
#define APIX (HT * WT)         // 64 prv pixels
#define BPIX (BROWS * BCOLS)   // 288 nxt pixels
#define ASTR 65                // odd granule stride (c8-major) for A
#define BSTR 289               // odd granule stride for B
#define NSA 2                  // A granule-slots per thread (64*8/256)
#define NSB 9                  // B granule-slots per thread (288*8/256)

typedef short short8 __attribute__((ext_vector_type(8)));
typedef short short4_t __attribute__((ext_vector_type(4)));
typedef float f32x4 __attribute__((ext_vector_type(4)));

static __device__ __forceinline__ short bf1(float f) {
    __hip_bfloat16 h = __float2bfloat16(f);   // pairs fuse to v_cvt_pk_bf16_f32
    return __builtin_bit_cast(short, h);
}

static __device__ __forceinline__ short4_t cvt4(float4 v) {
    short4_t r;
    r[0] = bf1(v.x); r[1] = bf1(v.y); r[2] = bf1(v.z); r[3] = bf1(v.w);
    return r;
}

static __device__ __forceinline__ short8 cat(short4_t u, short4_t v) {
    return __builtin_shufflevector(u, v, 0, 1, 2, 3, 4, 5, 6, 7);
}

__global__ __launch_bounds__(256, 5)
void cv_mfma(const float* __restrict__ prv, const float* __restrict__ nxt,
             float* __restrict__ out) {
    __shared__ short4_t sm[8 * ASTR + 8 * BSTR];   // 2832 granules = 22.7 KB
    short4_t* sA = sm;
    short4_t* sB = sm + 8 * ASTR;

    // ---- XCD-chunked decode: consecutive bids round-robin XCDs; give XCD k image k.
    const int bid = blockIdx.x;
    const int b   = bid & 7;           // batch image == XCD slot
    const int t   = bid >> 3;          // 0..255 tile within image, w-fastest
    const int w0  = (t & 7) * WT;
    const int h0  = (t >> 3) * HT;

    const int tid = threadIdx.x;
    const int lane = tid & 63;
    const int wid  = tid >> 6;      // 0..3: wave handles output row h0+wid
    const int lq = lane & 15;
    const int lc = lane >> 4;

    const int tp = tid >> 3;        // 0..31: pixel sub-index for staging
    const int c8 = tid & 7;         // 0..7: 4-channel granule index within kstep

    // ---- hoisted global element-offsets (k-step adds ks*KS)
    int aoff[NSA];
#pragma unroll
    for (int i = 0; i < NSA; ++i) {
        const int p = tp + 32 * i;        // 0..63
        const int r = p >> 4;
        const int pc = p & 15;
        aoff[i] = ((b * H_ + h0 + r) * W_ + w0 + pc) * C_ + c8 * 4;
    }
    int boff[NSB];
    unsigned bmask = 0;
#pragma unroll
    for (int i = 0; i < NSB; ++i) {
        const int p = tp + 32 * i;        // 0..287
        const int row = p / BCOLS;
        const int col = p - row * BCOLS;
        const int gh = h0 - 4 + row;
        const int gw = w0 - 4 + col;
        const bool ok = ((unsigned)gh < (unsigned)H_) && ((unsigned)gw < (unsigned)W_);
        if (ok) bmask |= (1u << i);
        boff[i] = ((b * H_ + (ok ? gh : 0)) * W_ + (ok ? gw : 0)) * C_ + c8 * 4;
    }

    f32x4 acc[ND][2];
#pragma unroll
    for (int d = 0; d < ND; ++d) {
        acc[d][0] = (f32x4){0.f, 0.f, 0.f, 0.f};
        acc[d][1] = (f32x4){0.f, 0.f, 0.f, 0.f};
    }

    for (int ks = 0; ks < NK; ++ks) {
        if (ks) __syncthreads();
        const int co = ks * KS;

        // ---- stage A: 2 coalesced dwordx4 per thread
        {
            float4 v0 = *(const float4*)(prv + aoff[0] + co);
            float4 v1 = *(const float4*)(prv + aoff[1] + co);
            sA[c8 * ASTR + tp]      = cvt4(v0);
            sA[c8 * ASTR + tp + 32] = cvt4(v1);
        }
        // ---- stage B: 9 slots in 3 batches of 3 (bounded reg pressure, batched ILP)
#pragma unroll
        for (int bt = 0; bt < 3; ++bt) {
            float4 v[3];
#pragma unroll
            for (int j = 0; j < 3; ++j) {
                const int i = 3 * bt + j;
                v[j] = make_float4(0.f, 0.f, 0.f, 0.f);
                if (bmask & (1u << i))
                    v[j] = *(const float4*)(nxt + boff[i] + co);
            }
#pragma unroll
            for (int j = 0; j < 3; ++j) {
                const int i = 3 * bt + j;
                sB[c8 * BSTR + tp + 32 * i] = cvt4(v[j]);
            }
        }
        __syncthreads();

        // ---- A frag: channels co + 8*lc .. +7 = granules 2lc, 2lc+1 of pixel (wid, w0+lq)
        const int pA = wid * WT + lq;
        const short8 a = cat(sA[2 * lc * ASTR + pA], sA[(2 * lc + 1) * ASTR + pA]);

        // ---- compute: 9 dy x 2 col-tiles (single K=32 sub-step)
#pragma unroll
        for (int dy = 0; dy < ND; ++dy) {
            const int pp0 = (wid + dy) * BCOLS + lq;
            const short8 b0 = cat(sB[2 * lc * BSTR + pp0],     sB[(2 * lc + 1) * BSTR + pp0]);
            const short8 b1 = cat(sB[2 * lc * BSTR + pp0 + 8], sB[(2 * lc + 1) * BSTR + pp0 + 8]);
            acc[dy][0] = __builtin_amdgcn_mfma_f32_16x16x32_bf16(a, b0, acc[dy][0], 0, 0, 0);
            acc[dy][1] = __builtin_amdgcn_mfma_f32_16x16x32_bf16(a, b1, acc[dy][1], 0, 0, 0);
        }
    }

    // ---- epilogue (identical to R5/R10, verified): D layout col=lane&15, row=4*(lane>>4)+reg.
    // rows r<8 valid in tile0 (dx=q-r), rows r>=8 in tile1 (dx=q-r+8).
    const float inv = 1.0f / (float)C_;
    const int h = h0 + wid;
    if (lc < 2) {
#pragma unroll
        for (int rg = 0; rg < 4; ++rg) {
            const int r = 4 * lc + rg;
            const int dx = lq - r;
            if (dx >= 0 && dx <= 8) {
                float* o = out + (size_t)((b * H_ + h) * W_ + w0 + r) * NDISP + dx;
#pragma unroll
                for (int dy = 0; dy < ND; ++dy) {
                    const float v = acc[dy][0][rg] * inv;
                    o[dy * ND] = v >= 0.f ? v : 0.1f * v;
                }
            }
        }
    } else {
#pragma unroll
        for (int rg = 0; rg < 4; ++rg) {
            const int r = 4 * lc + rg;
            const int dx = lq - r + 8;
            if (dx >= 0 && dx <= 8) {
                float* o = out + (size_t)((b * H_ + h) * W_ + w0 + r) * NDISP + dx;
#pragma unroll
                for (int dy = 0; dy < ND; ++dy) {
                    const float v = acc[dy][1][rg] * inv;
                    o[dy * ND] = v >= 0.f ? v : 0.1f * v;
                }
            }
        }
    }
}

extern "C" void kernel_launch(void* const* d_in, const int* in_sizes, int n_in,
                              void* d_out, int out_size, void* d_ws, size_t ws_size,
                              hipStream_t stream) {
    const float* prv = (const float*)d_in[0];
    const float* nxt = (const float*)d_in[1];
    float* out = (float*)d_out;

    cv_mfma<<<dim3(2048), 256, 0, stream>>>(prv, nxt, out);   // 8 XCD-chunks x 256 tiles
}

// Round 12
// 74.631 us; speedup vs baseline: 1.7281x; 1.7281x over previous
//
#include <hip/hip_runtime.h>
#include <hip/hip_bf16.h>

// out[b,h,w,dy*9+dx] = leaky_relu( mean_c( prv[b,h,w,c] * nxt[b,h+dy-4,w+dx-4,c] ), 0.1 )
// R12: issued-byte minimization. 16x16 output tile (halo 2.25x vs R10's 4.5x),
// 8 waves x 512 thr, wave owns 2 h-rows; coalesced granule staging (R10-verified),
// banded 16x16x32 MFMA pair per (row,dy) (R5-verified epilogue partition).
// Model: time ~ issued-load-bytes / (10 B/cyc/CU): 354 MB -> ~58 us.

#define B_ 8
#define H_ 128
#define W_ 128
#define C_ 192
#define ND 9
#define NDISP 81
#define HT 16           // tile rows
#define WT 16           // tile cols
#define KS 32           // channels per k-step
#define NK 6            // 192/32
#define BROWS 24        // HT+8 staged nxt rows
#define BCOLS 24        // WT+8 staged nxt cols
#define APIX (HT * WT)         // 256
#define BPIX (BROWS * BCOLS)   // 576
#define ASTR 257               // odd 8B-slot stride (granule-major) for A
#define BSTR 577               // odd stride for B
#define NSA 4                  // A granule-slots per thread (256*8/512)
#define NSB 9                  // B granule-slots per thread (576*8/512)

typedef short short8 __attribute__((ext_vector_type(8)));
typedef short short4_t __attribute__((ext_vector_type(4)));
typedef float f32x4 __attribute__((ext_vector_type(4)));

static __device__ __forceinline__ short bf1(float f) {
    __hip_bfloat16 h = __float2bfloat16(f);   // pairs fuse to v_cvt_pk_bf16_f32
    return __builtin_bit_cast(short, h);
}

static __device__ __forceinline__ short4_t cvt4(float4 v) {
    short4_t r;
    r[0] = bf1(v.x); r[1] = bf1(v.y); r[2] = bf1(v.z); r[3] = bf1(v.w);
    return r;
}

static __device__ __forceinline__ short8 cat(short4_t u, short4_t v) {
    return __builtin_shufflevector(u, v, 0, 1, 2, 3, 4, 5, 6, 7);
}

__global__ __launch_bounds__(512, 2)
void cv_mfma(const float* __restrict__ prv, const float* __restrict__ nxt,
             float* __restrict__ out) {
    // LDS: granule-major [c8][pixel], 8B short4 slots, odd strides -> conflict-light.
    __shared__ short4_t sm[8 * ASTR + 8 * BSTR];   // 6672 slots = 53.4 KB
    short4_t* sA = sm;
    short4_t* sB = sm + 8 * ASTR;

    const int tid = threadIdx.x;
    const int w0 = blockIdx.x * WT;
    const int h0 = blockIdx.y * HT;
    const int b  = blockIdx.z;

    const int lane = tid & 63;
    const int wid  = tid >> 6;      // 0..7: wave owns rows 2*wid, 2*wid+1
    const int lq = lane & 15;
    const int lc = lane >> 4;

    const int tp = tid >> 3;        // 0..63: pixel sub-index for staging
    const int c8 = tid & 7;         // 0..7: 4-channel granule within k-step

    // ---- hoisted global element-offsets (k-step adds ks*KS)
    int aoff[NSA];
#pragma unroll
    for (int i = 0; i < NSA; ++i) {
        const int p = tp + 64 * i;        // 0..255
        const int r = p >> 4;
        const int pc = p & 15;
        aoff[i] = ((b * H_ + h0 + r) * W_ + w0 + pc) * C_ + c8 * 4;
    }
    int boff[NSB];
    unsigned bmask = 0;
#pragma unroll
    for (int i = 0; i < NSB; ++i) {
        const int p = tp + 64 * i;        // 0..575
        const int row = p / BCOLS;
        const int col = p - row * BCOLS;
        const int gh = h0 - 4 + row;
        const int gw = w0 - 4 + col;
        const bool ok = ((unsigned)gh < (unsigned)H_) && ((unsigned)gw < (unsigned)W_);
        if (ok) bmask |= (1u << i);
        boff[i] = ((b * H_ + (ok ? gh : 0)) * W_ + (ok ? gw : 0)) * C_ + c8 * 4;
    }

    f32x4 acc[2][ND][2];
#pragma unroll
    for (int u = 0; u < 2; ++u)
#pragma unroll
        for (int d = 0; d < ND; ++d) {
            acc[u][d][0] = (f32x4){0.f, 0.f, 0.f, 0.f};
            acc[u][d][1] = (f32x4){0.f, 0.f, 0.f, 0.f};
        }

    for (int ks = 0; ks < NK; ++ks) {
        if (ks) __syncthreads();
        const int co = ks * KS;

        // ---- stage A: 4 coalesced dwordx4 per thread (batched issue)
        {
            float4 v[NSA];
#pragma unroll
            for (int i = 0; i < NSA; ++i)
                v[i] = *(const float4*)(prv + aoff[i] + co);
#pragma unroll
            for (int i = 0; i < NSA; ++i)
                sA[c8 * ASTR + tp + 64 * i] = cvt4(v[i]);
        }
        // ---- stage B: 9 slots in 3 batches of 3
#pragma unroll
        for (int bt = 0; bt < 3; ++bt) {
            float4 v[3];
#pragma unroll
            for (int j = 0; j < 3; ++j) {
                const int i = 3 * bt + j;
                v[j] = make_float4(0.f, 0.f, 0.f, 0.f);
                if (bmask & (1u << i))
                    v[j] = *(const float4*)(nxt + boff[i] + co);
            }
#pragma unroll
            for (int j = 0; j < 3; ++j) {
                const int i = 3 * bt + j;
                sB[c8 * BSTR + tp + 64 * i] = cvt4(v[j]);
            }
        }
        __syncthreads();

        // ---- compute: 2 row-units x 9 dy x 2 col-tiles
#pragma unroll
        for (int u = 0; u < 2; ++u) {
            const int r = 2 * wid + u;
            const int pA = r * WT + lq;
            const short8 a = cat(sA[2 * lc * ASTR + pA], sA[(2 * lc + 1) * ASTR + pA]);
#pragma unroll
            for (int dy = 0; dy < ND; ++dy) {
                const int pB = (r + dy) * BCOLS + lq;
                const short8 b0 = cat(sB[2 * lc * BSTR + pB],     sB[(2 * lc + 1) * BSTR + pB]);
                const short8 b1 = cat(sB[2 * lc * BSTR + pB + 8], sB[(2 * lc + 1) * BSTR + pB + 8]);
                acc[u][dy][0] = __builtin_amdgcn_mfma_f32_16x16x32_bf16(a, b0, acc[u][dy][0], 0, 0, 0);
                acc[u][dy][1] = __builtin_amdgcn_mfma_f32_16x16x32_bf16(a, b1, acc[u][dy][1], 0, 0, 0);
            }
        }
    }

    // ---- epilogue (R5-verified partition): D col=lane&15 (q), D row=4*lc+rg (rD =
    // w-position). rows rD<8 from tile0 (dx=q-rD), rD>=8 from tile1 (dx=q-rD+8).
    const float inv = 1.0f / (float)C_;
#pragma unroll
    for (int u = 0; u < 2; ++u) {
        const int h = h0 + 2 * wid + u;
        if (lc < 2) {
#pragma unroll
            for (int rg = 0; rg < 4; ++rg) {
                const int rD = 4 * lc + rg;
                const int dx = lq - rD;
                if (dx >= 0 && dx <= 8) {
                    float* o = out + (size_t)((b * H_ + h) * W_ + w0 + rD) * NDISP + dx;
#pragma unroll
                    for (int dy = 0; dy < ND; ++dy) {
                        const float v = acc[u][dy][0][rg] * inv;
                        o[dy * ND] = v >= 0.f ? v : 0.1f * v;
                    }
                }
            }
        } else {
#pragma unroll
            for (int rg = 0; rg < 4; ++rg) {
                const int rD = 4 * (lc - 2) + rg + 8;
                const int dx = lq - rD + 8;
                if (dx >= 0 && dx <= 8) {
                    float* o = out + (size_t)((b * H_ + h) * W_ + w0 + rD) * NDISP + dx;
#pragma unroll
                    for (int dy = 0; dy < ND; ++dy) {
                        const float v = acc[u][dy][1][rg] * inv;
                        o[dy * ND] = v >= 0.f ? v : 0.1f * v;
                    }
                }
            }
        }
    }
}

extern "C" void kernel_launch(void* const* d_in, const int* in_sizes, int n_in,
                              void* d_out, int out_size, void* d_ws, size_t ws_size,
                              hipStream_t stream) {
    const float* prv = (const float*)d_in[0];
    const float* nxt = (const float*)d_in[1];
    float* out = (float*)d_out;

    dim3 grid(W_ / WT, H_ / HT, B_);   // (8, 8, 8) = 512 blocks x 512 threads
    cv_mfma<<<grid, 512, 0, stream>>>(prv, nxt, out);
}